// Round 1
// baseline (172400.000 us; speedup 1.0000x reference)
//
#include <hip/hip_runtime.h>
#include <math.h>

#define Bc 64
#define Lc 256
#define Ec 512
#define Hc 1024
#define Nc 128
#define HSc 64
#define NHc 4
#define INDIMc 768
#define PODc 1280
#define OUTDc 1024

// ---------- helpers ----------
__device__ inline float sigm(float x) { return 1.0f / (1.0f + expf(-x)); }

__device__ inline float wsum(float v) {
#pragma unroll
  for (int o = 32; o > 0; o >>= 1) v += __shfl_xor(v, o, 64);
  return v;
}

// ---------- kernel 1: input LN + gate GEMV ----------
// grid (64 jt, 64 b), block 256
__global__ __launch_bounds__(256) void k_gates(
    const float* __restrict__ xemb, const float* __restrict__ rcbuf,
    const float* __restrict__ hbuf,
    const float* __restrict__ in_g, const float* __restrict__ in_b,
    const float* __restrict__ W_ih, const float* __restrict__ W_hh,
    const float* __restrict__ b_ih, const float* __restrict__ b_hh,
    float* __restrict__ gates, int t)
{
  __shared__ float sIn[1792];
  __shared__ float rs[4], rq[4];
  int b = blockIdx.y, tid = threadIdx.x, lane = tid & 63, wid = tid >> 6;
  float v3[3]; float s = 0.f, sq = 0.f;
#pragma unroll
  for (int i = 0; i < 3; i++) {
    int k = tid + i * 256;
    float v = (k < Ec) ? xemb[(b * Lc + t) * Ec + k] : rcbuf[b * 256 + (k - Ec)];
    v3[i] = v; s += v; sq += v * v;
  }
  s = wsum(s); sq = wsum(sq);
  if (lane == 0) { rs[wid] = s; rq[wid] = sq; }
  __syncthreads();
  float ts = rs[0] + rs[1] + rs[2] + rs[3];
  float tq = rq[0] + rq[1] + rq[2] + rq[3];
  float mu = ts / 768.f, var = tq / 768.f - mu * mu;
  float rstd = rsqrtf(var + 1e-5f);
#pragma unroll
  for (int i = 0; i < 3; i++) {
    int k = tid + i * 256;
    sIn[k] = (v3[i] - mu) * rstd * in_g[k] + in_b[k];
  }
  for (int k = tid; k < 1024; k += 256) sIn[768 + k] = hbuf[b * 1024 + k];
  __syncthreads();
  int j0 = blockIdx.x * 64;
  for (int i = 0; i < 16; i++) {
    int j = j0 + wid * 16 + i;
    const float* wih = W_ih + (size_t)j * 768;
    const float* whh = W_hh + (size_t)j * 1024;
    float acc = 0.f;
#pragma unroll 4
    for (int k0 = 0; k0 < 768; k0 += 64) acc += wih[k0 + lane] * sIn[k0 + lane];
#pragma unroll 4
    for (int k0 = 0; k0 < 1024; k0 += 64) acc += whh[k0 + lane] * sIn[768 + k0 + lane];
#pragma unroll
    for (int o = 32; o > 0; o >>= 1) acc += __shfl_down(acc, o, 64);
    if (lane == 0) gates[b * 4096 + j] = acc + b_ih[j] + b_hh[j];
  }
}

// ---------- kernel 2: LSTM cell + hn LayerNorm ----------
// grid 64 (b), block 256
__global__ __launch_bounds__(256) void k_lstm(
    const float* __restrict__ gates, float* __restrict__ cbuf, float* __restrict__ hbuf,
    const float* __restrict__ cn_g, const float* __restrict__ cn_b,
    float* __restrict__ hn)
{
  __shared__ float rs[4], rq[4];
  int b = blockIdx.x, tid = threadIdx.x, lane = tid & 63, wid = tid >> 6;
  float hv[4]; float s = 0.f, sq = 0.f;
  const float* g = gates + b * 4096;
#pragma unroll
  for (int i = 0; i < 4; i++) {
    int u = tid + i * 256;
    float gi = g[u], gf = g[1024 + u], gg = g[2048 + u], go = g[3072 + u];
    float cn = sigm(gf) * cbuf[b * 1024 + u] + sigm(gi) * tanhf(gg);
    float hh = sigm(go) * tanhf(cn);
    cbuf[b * 1024 + u] = cn; hbuf[b * 1024 + u] = hh;
    hv[i] = hh; s += hh; sq += hh * hh;
  }
  s = wsum(s); sq = wsum(sq);
  if (lane == 0) { rs[wid] = s; rq[wid] = sq; }
  __syncthreads();
  float ts = rs[0] + rs[1] + rs[2] + rs[3];
  float tq = rq[0] + rq[1] + rq[2] + rq[3];
  float mu = ts / 1024.f, var = tq / 1024.f - mu * mu;
  float rstd = rsqrtf(var + 1e-5f);
#pragma unroll
  for (int i = 0; i < 4; i++) {
    int u = tid + i * 256;
    hn[b * 1024 + u] = (hv[i] - mu) * rstd * cn_g[u] + cn_b[u];
  }
}

// ---------- kernel 3: head GEMVs + key LN + sigmoids ----------
// grid (13, 64 b), block 256
__global__ __launch_bounds__(256) void k_heads(
    const float* __restrict__ hn,
    const float* __restrict__ W_rk, const float* __restrict__ b_rk,
    const float* __restrict__ W_wk, const float* __restrict__ b_wk,
    const float* __restrict__ W_ws, const float* __restrict__ b_ws,
    const float* __restrict__ W_ev, const float* __restrict__ b_ev,
    const float* __restrict__ rkn_g, const float* __restrict__ rkn_b,
    const float* __restrict__ wkn_g, const float* __restrict__ wkn_b,
    float* __restrict__ rkn, float* __restrict__ wkn,
    float* __restrict__ evb, float* __restrict__ ws4)
{
  __shared__ float sHn[1024];
  __shared__ float sOut[64];
  int b = blockIdx.y, bi = blockIdx.x, tid = threadIdx.x;
  int lane = tid & 63, wid = tid >> 6;
  for (int k = tid; k < 1024; k += 256) sHn[k] = hn[b * 1024 + k];
  __syncthreads();
  if (bi < 12) {
    int a = bi >> 2;   // 0 rk, 1 wk, 2 ev
    int n = bi & 3;    // head
    const float* W = (a == 0) ? W_rk : (a == 1) ? W_wk : W_ev;
    const float* bias = (a == 0) ? b_rk : (a == 1) ? b_wk : b_ev;
    for (int i = 0; i < 16; i++) {
      int col = wid * 16 + i;
      int row = n * 64 + col;
      const float* wr = W + (size_t)row * 1024;
      float acc = 0.f;
#pragma unroll 4
      for (int k0 = 0; k0 < 1024; k0 += 64) acc += wr[k0 + lane] * sHn[k0 + lane];
#pragma unroll
      for (int o = 32; o > 0; o >>= 1) acc += __shfl_down(acc, o, 64);
      if (lane == 0) sOut[col] = acc + bias[row];
    }
    __syncthreads();
    if (tid < 64) {
      float v = sOut[tid];
      if (a == 2) {
        evb[b * 256 + n * 64 + tid] = sigm(v);
      } else {
        float ssum = wsum(v), ssq = wsum(v * v);
        float mu = ssum / 64.f, var = ssq / 64.f - mu * mu;
        float rstd = rsqrtf(var + 1e-5f);
        float gg = (a == 0) ? rkn_g[tid] : wkn_g[tid];
        float bb = (a == 0) ? rkn_b[tid] : wkn_b[tid];
        float r = (v - mu) * rstd * gg + bb;
        if (a == 0) rkn[b * 256 + n * 64 + tid] = r;
        else        wkn[b * 256 + n * 64 + tid] = r;
      }
    }
  } else {
    int n = wid; // 0..3
    const float* wr = W_ws + (size_t)n * 1024;
    float acc = 0.f;
#pragma unroll 4
    for (int k0 = 0; k0 < 1024; k0 += 64) acc += wr[k0 + lane] * sHn[k0 + lane];
#pragma unroll
    for (int o = 32; o > 0; o >>= 1) acc += __shfl_down(acc, o, 64);
    if (lane == 0) ws4[b * 4 + n] = sigm(acc + b_ws[n]);
  }
}

// ---------- kernel 4: transformer block on memory ----------
// grid 64 (b), block 512, 128KB LDS
__global__ __launch_bounds__(512) void k_tblock(
    const float* __restrict__ mem,
    const float* __restrict__ attn_w, const float* __restrict__ attn_b,
    const float* __restrict__ attn_ow, const float* __restrict__ attn_ob,
    const float* __restrict__ l1w, const float* __restrict__ l1b,
    const float* __restrict__ l2w, const float* __restrict__ l2b,
    const float* __restrict__ tn1g, const float* __restrict__ tn1b,
    const float* __restrict__ tn2g, const float* __restrict__ tn2b,
    float* __restrict__ memT)
{
  __shared__ float pool[32768];
  float* sMem = pool;            // [128][64]
  float* sQ = pool + 8192;       // [128][64]
  float* sK = pool + 16384;      // [128][64]
  float* sV = pool + 24576;      // [128][64]
  int b = blockIdx.x, tid = threadIdx.x, lane = tid & 63, wid = tid >> 6;
  const float* mb = mem + (size_t)b * 8192;
  for (int i = tid; i < 8192; i += 512) sMem[i] = mb[i];
  __syncthreads();
  // qkv
  for (int idx = tid; idx < 24576; idx += 512) {
    int m = idx / 192, j = idx % 192;
    const float* wr = attn_w + j * 64;
    const float* mr = sMem + m * 64;
    float acc = attn_b[j];
#pragma unroll 8
    for (int s = 0; s < 64; s++) acc += mr[s] * wr[s];
    if (j < 64) sQ[m * 64 + j] = acc;
    else if (j < 128) sK[m * 64 + j - 64] = acc;
    else sV[m * 64 + j - 128] = acc;
  }
  __syncthreads();
  // attention: thread = one (m, head); wave shares head -> K/V reads broadcast
  int hd = tid >> 7, m = tid & 127;
  float qr[16];
#pragma unroll
  for (int d = 0; d < 16; d++) qr[d] = sQ[m * 64 + hd * 16 + d];
  float mx = -1e30f;
  for (int km = 0; km < 128; km++) {
    const float* kr = sK + km * 64 + hd * 16;
    float sc = 0.f;
#pragma unroll
    for (int d = 0; d < 16; d++) sc += qr[d] * kr[d];
    mx = fmaxf(mx, sc * 0.25f);
  }
  float o[16];
#pragma unroll
  for (int d = 0; d < 16; d++) o[d] = 0.f;
  float sum = 0.f;
  for (int km = 0; km < 128; km++) {
    const float* kr = sK + km * 64 + hd * 16;
    float sc = 0.f;
#pragma unroll
    for (int d = 0; d < 16; d++) sc += qr[d] * kr[d];
    float e = expf(sc * 0.25f - mx);
    sum += e;
    const float* vr = sV + km * 64 + hd * 16;
#pragma unroll
    for (int d = 0; d < 16; d++) o[d] += e * vr[d];
  }
  float inv = 1.0f / sum;
  __syncthreads();
#pragma unroll
  for (int d = 0; d < 16; d++) sQ[m * 64 + hd * 16 + d] = o[d] * inv;
  __syncthreads();
  // out proj + residual -> sK
  for (int idx = tid; idx < 8192; idx += 512) {
    int mm = idx >> 6, j = idx & 63;
    const float* wr = attn_ow + j * 64;
    const float* orow = sQ + mm * 64;
    float acc = attn_ob[j];
#pragma unroll 8
    for (int s = 0; s < 64; s++) acc += orow[s] * wr[s];
    sK[idx] = sMem[idx] + acc;
  }
  __syncthreads();
  // ln1 -> sQ
  for (int r = wid; r < 128; r += 8) {
    float v = sK[r * 64 + lane];
    float ssum = wsum(v), ssq = wsum(v * v);
    float mu = ssum * (1.f / 64), var = ssq * (1.f / 64) - mu * mu;
    sQ[r * 64 + lane] = (v - mu) * rsqrtf(var + 1e-5f) * tn1g[lane] + tn1b[lane];
  }
  __syncthreads();
  // ff1 (gelu) -> sF [128][128]
  float* sF = pool + 16384;
  for (int idx = tid; idx < 16384; idx += 512) {
    int mm = idx >> 7, j = idx & 127;
    const float* wr = l1w + j * 64;
    const float* xr = sQ + mm * 64;
    float acc = l1b[j];
#pragma unroll 8
    for (int s = 0; s < 64; s++) acc += xr[s] * wr[s];
    sF[idx] = 0.5f * acc * (1.0f + erff(acc * 0.70710678118654752f));
  }
  __syncthreads();
  // ff2 + residual -> sMem
  for (int idx = tid; idx < 8192; idx += 512) {
    int mm = idx >> 6, j = idx & 63;
    const float* wr = l2w + j * 128;
    const float* fr = sF + mm * 128;
    float acc = l2b[j];
#pragma unroll 8
    for (int s = 0; s < 128; s++) acc += fr[s] * wr[s];
    sMem[idx] = sQ[idx] + acc;
  }
  __syncthreads();
  // ln2 -> memT
  float* outp = memT + (size_t)b * 8192;
  for (int r = wid; r < 128; r += 8) {
    float v = sMem[r * 64 + lane];
    float ssum = wsum(v), ssq = wsum(v * v);
    float mu = ssum * (1.f / 64), var = ssq * (1.f / 64) - mu * mu;
    outp[r * 64 + lane] = (v - mu) * rsqrtf(var + 1e-5f) * tn2g[lane] + tn2b[lane];
  }
}

// ---------- kernel 5: NTM addressing + mem update + output LN ----------
// grid 64 (b), block 256
__global__ __launch_bounds__(256) void k_address(
    const float* __restrict__ memT,
    const float* __restrict__ rkn, const float* __restrict__ wkn,
    const float* __restrict__ evb, const float* __restrict__ ws4,
    const float* __restrict__ hn,
    const float* __restrict__ mng, const float* __restrict__ mnb,
    const float* __restrict__ pog, const float* __restrict__ pob,
    float* __restrict__ mem, float* __restrict__ rcb, float* __restrict__ pobuf)
{
  __shared__ float sMT[8192], sMN[8192];
  __shared__ float sRk[256], sWk[256], sEv[256], sWs[4];
  __shared__ float sRw[512], sWw[512], sRc[256];
  __shared__ float rs[4], rq[4];
  int b = blockIdx.x, tid = threadIdx.x, lane = tid & 63, wid = tid >> 6;
  for (int i = tid; i < 8192; i += 256) sMT[i] = memT[(size_t)b * 8192 + i];
  if (tid < 256) { sRk[tid] = rkn[b * 256 + tid]; sWk[tid] = wkn[b * 256 + tid]; sEv[tid] = evb[b * 256 + tid]; }
  if (tid < 4) sWs[tid] = ws4[b * 4 + tid];
  __syncthreads();
  // mem_n = ln(memT)
  for (int r = wid; r < 128; r += 4) {
    float v = sMT[r * 64 + lane];
    float ssum = wsum(v), ssq = wsum(v * v);
    float mu = ssum * (1.f / 64), var = ssq * (1.f / 64) - mu * mu;
    sMN[r * 64 + lane] = (v - mu) * rsqrtf(var + 1e-5f) * mng[lane] + mnb[lane];
  }
  __syncthreads();
  // scores rw / ww
#pragma unroll
  for (int q = 0; q < 4; q++) {
    int idx = tid + q * 256;            // 0..1023
    int which = idx >> 9;               // 0 rw, 1 ww
    int n = (idx >> 7) & 3, m = idx & 127;
    const float* key = (which ? sWk : sRk) + n * 64;
    const float* mr = sMN + m * 64;
    float acc = 0.f;
#pragma unroll 8
    for (int k = 0; k < 64; k++) acc += key[k] * mr[k];
    (which ? sWw : sRw)[n * 128 + m] = acc;
  }
  __syncthreads();
  // softmax rows (8 rows of 128)
  for (int r = wid; r < 8; r += 4) {
    float* row = (r < 4) ? (sRw + r * 128) : (sWw + (r - 4) * 128);
    float a0 = row[lane], a1 = row[lane + 64];
    float mx = fmaxf(a0, a1);
#pragma unroll
    for (int o = 32; o > 0; o >>= 1) mx = fmaxf(mx, __shfl_xor(mx, o, 64));
    float e0 = expf(a0 - mx), e1 = expf(a1 - mx);
    float ssum = wsum(e0 + e1);
    float inv = 1.0f / ssum;
    row[lane] = e0 * inv; row[lane + 64] = e1 * inv;
  }
  __syncthreads();
  // rc = rw @ memT
  {
    int n = tid >> 6, s = tid & 63;
    float acc = 0.f;
    for (int mm = 0; mm < 128; mm++) acc += sRw[n * 128 + mm] * sMT[mm * 64 + s];
    sRc[tid] = acc;
    rcb[b * 256 + tid] = acc;
  }
  __syncthreads();
  // mem update: erase + add
  for (int idx = tid; idx < 8192; idx += 256) {
    int mm = idx >> 6, s = idx & 63;
    float er = 0.f, ad = 0.f;
#pragma unroll
    for (int n = 0; n < 4; n++) {
      float w = sWw[n * 128 + mm];
      er += w * sEv[n * 64 + s];
      ad += w * sWs[n] * sWk[n * 64 + s];
    }
    mem[(size_t)b * 8192 + idx] = sMT[idx] * (1.0f - er) + ad;
  }
  // output LN over 1280 = [hn | rc]
  float v5[5]; float s = 0.f, sq = 0.f;
#pragma unroll
  for (int i = 0; i < 5; i++) {
    int k = tid + i * 256;
    float v = (k < 1024) ? hn[b * 1024 + k] : sRc[k - 1024];
    v5[i] = v; s += v; sq += v * v;
  }
  s = wsum(s); sq = wsum(sq);
  if (lane == 0) { rs[wid] = s; rq[wid] = sq; }
  __syncthreads();
  float ts = rs[0] + rs[1] + rs[2] + rs[3];
  float tq = rq[0] + rq[1] + rq[2] + rq[3];
  float mu = ts / 1280.f, var = tq / 1280.f - mu * mu;
  float rstd = rsqrtf(var + 1e-5f);
#pragma unroll
  for (int i = 0; i < 5; i++) {
    int k = tid + i * 256;
    pobuf[b * 1280 + k] = (v5[i] - mu) * rstd * pog[k] + pob[k];
  }
}

// ---------- kernel 6: logits GEMV ----------
// grid (16, 64 b), block 256
__global__ __launch_bounds__(256) void k_logits(
    const float* __restrict__ pobuf, const float* __restrict__ W_proj,
    const float* __restrict__ b_proj, float* __restrict__ outs, int t)
{
  __shared__ float sPo[1280];
  int b = blockIdx.y, tid = threadIdx.x, lane = tid & 63, wid = tid >> 6;
  for (int k = tid; k < 1280; k += 256) sPo[k] = pobuf[b * 1280 + k];
  __syncthreads();
  int j0 = blockIdx.x * 64;
  for (int i = 0; i < 16; i++) {
    int j = j0 + wid * 16 + i;
    const float* wr = W_proj + (size_t)j * 1280;
    float acc = 0.f;
#pragma unroll 4
    for (int k0 = 0; k0 < 1280; k0 += 64) acc += wr[k0 + lane] * sPo[k0 + lane];
#pragma unroll
    for (int o = 32; o > 0; o >>= 1) acc += __shfl_down(acc, o, 64);
    if (lane == 0) outs[((size_t)b * Lc + t) * OUTDc + j] = acc + b_proj[j];
  }
}

// ---------- final: copy mem/h/c to output ----------
__global__ void k_final(const float* __restrict__ mem, const float* __restrict__ h,
                        const float* __restrict__ c, float* __restrict__ out)
{
  int i = blockIdx.x * 256 + threadIdx.x;
  if (i < 524288) out[16777216 + i] = mem[i];
  if (i < 65536) {
    out[17301504 + i] = h[i];
    out[17367040 + i] = c[i];
  }
}

extern "C" void kernel_launch(void* const* d_in, const int* in_sizes, int n_in,
                              void* d_out, int out_size, void* d_ws, size_t ws_size,
                              hipStream_t stream) {
  const float* x_emb  = (const float*)d_in[0];
  const float* in_g   = (const float*)d_in[1];
  const float* in_b   = (const float*)d_in[2];
  const float* W_ih   = (const float*)d_in[3];
  const float* W_hh   = (const float*)d_in[4];
  const float* b_ih   = (const float*)d_in[5];
  const float* b_hh   = (const float*)d_in[6];
  const float* cn_g   = (const float*)d_in[7];
  const float* cn_b   = (const float*)d_in[8];
  const float* W_rk   = (const float*)d_in[9];
  const float* b_rk   = (const float*)d_in[10];
  const float* W_wk   = (const float*)d_in[11];
  const float* b_wk   = (const float*)d_in[12];
  const float* W_ws   = (const float*)d_in[13];
  const float* b_ws   = (const float*)d_in[14];
  const float* W_ev   = (const float*)d_in[15];
  const float* b_ev   = (const float*)d_in[16];
  const float* attn_w = (const float*)d_in[17];
  const float* attn_b = (const float*)d_in[18];
  const float* attn_ow= (const float*)d_in[19];
  const float* attn_ob= (const float*)d_in[20];
  const float* l1_w   = (const float*)d_in[21];
  const float* l1_b   = (const float*)d_in[22];
  const float* l2_w   = (const float*)d_in[23];
  const float* l2_b   = (const float*)d_in[24];
  const float* tn1_g  = (const float*)d_in[25];
  const float* tn1_b  = (const float*)d_in[26];
  const float* tn2_g  = (const float*)d_in[27];
  const float* tn2_b  = (const float*)d_in[28];
  const float* rkn_g  = (const float*)d_in[29];
  const float* rkn_b  = (const float*)d_in[30];
  const float* wkn_g  = (const float*)d_in[31];
  const float* wkn_b  = (const float*)d_in[32];
  const float* mn_g   = (const float*)d_in[33];
  const float* mn_b   = (const float*)d_in[34];
  const float* po_g   = (const float*)d_in[35];
  const float* po_b   = (const float*)d_in[36];
  const float* W_proj = (const float*)d_in[37];
  const float* b_proj = (const float*)d_in[38];

  float* ws   = (float*)d_ws;
  float* gates = ws;               // 262144
  float* hbuf  = ws + 262144;      // 65536
  float* cbuf  = ws + 327680;      // 65536
  float* hn    = ws + 393216;      // 65536
  float* rkn   = ws + 458752;      // 16384
  float* wkn   = ws + 475136;      // 16384
  float* evb   = ws + 491520;      // 16384
  float* ws4   = ws + 507904;      // 256
  float* mem   = ws + 508160;      // 524288
  float* memT  = ws + 1032448;     // 524288
  float* rcb   = ws + 1556736;     // 16384
  float* pobuf = ws + 1573120;     // 81920  (end 1655040)

  float* outs = (float*)d_out;

  hipMemsetAsync(d_ws, 0, 1655040 * sizeof(float), stream);

  for (int t = 0; t < Lc; t++) {
    k_tblock<<<dim3(64), dim3(512), 0, stream>>>(mem, attn_w, attn_b, attn_ow, attn_ob,
                                                 l1_w, l1_b, l2_w, l2_b,
                                                 tn1_g, tn1_b, tn2_g, tn2_b, memT);
    k_gates<<<dim3(64, 64), dim3(256), 0, stream>>>(x_emb, rcb, hbuf, in_g, in_b,
                                                    W_ih, W_hh, b_ih, b_hh, gates, t);
    k_lstm<<<dim3(64), dim3(256), 0, stream>>>(gates, cbuf, hbuf, cn_g, cn_b, hn);
    k_heads<<<dim3(13, 64), dim3(256), 0, stream>>>(hn, W_rk, b_rk, W_wk, b_wk,
                                                    W_ws, b_ws, W_ev, b_ev,
                                                    rkn_g, rkn_b, wkn_g, wkn_b,
                                                    rkn, wkn, evb, ws4);
    k_address<<<dim3(64), dim3(256), 0, stream>>>(memT, rkn, wkn, evb, ws4, hn,
                                                  mn_g, mn_b, po_g, po_b,
                                                  mem, rcb, pobuf);
    k_logits<<<dim3(16, 64), dim3(256), 0, stream>>>(pobuf, W_proj, b_proj, outs, t);
  }
  k_final<<<dim3(2048), dim3(256), 0, stream>>>(mem, hbuf, cbuf, (float*)d_out);
}

// Round 2
// 41604.681 us; speedup vs baseline: 4.1438x; 4.1438x over previous
//
#include <hip/hip_runtime.h>
#include <math.h>

// ---------- helpers ----------
__device__ inline float sigm(float x) { return 1.0f / (1.0f + expf(-x)); }
__device__ inline float dot4(const float4 a, const float4 b) {
  return a.x*b.x + a.y*b.y + a.z*b.z + a.w*b.w;
}
__device__ inline float wsum(float v) {
#pragma unroll
  for (int o = 32; o > 0; o >>= 1) v += __shfl_xor(v, o, 64);
  return v;
}

// ---------- prologue: xin for t=0 (rc=0) ----------
__global__ __launch_bounds__(256) void k_prep0(
    const float* __restrict__ x_emb, const float* __restrict__ in_g,
    const float* __restrict__ in_b, float* __restrict__ inbuf)
{
  __shared__ float rs[4], rq[4];
  int b = blockIdx.x, tid = threadIdx.x, lane = tid & 63, wid = tid >> 6;
  float v3[3]; float s = 0.f, sq = 0.f;
#pragma unroll
  for (int i = 0; i < 3; i++) {
    int k = tid + i * 256;
    float v = (k < 512) ? x_emb[(size_t)b * 256 * 512 + k] : 0.f;
    v3[i] = v; s += v; sq += v * v;
  }
  s = wsum(s); sq = wsum(sq);
  if (lane == 0) { rs[wid] = s; rq[wid] = sq; }
  __syncthreads();
  float ts = rs[0]+rs[1]+rs[2]+rs[3], tq = rq[0]+rq[1]+rq[2]+rq[3];
  float mu = ts / 768.f, var = tq / 768.f - mu * mu;
  float rstd = rsqrtf(var + 1e-5f);
#pragma unroll
  for (int i = 0; i < 3; i++) {
    int k = tid + i * 256;
    inbuf[b * 1792 + k] = (v3[i] - mu) * rstd * in_g[k] + in_b[k];
  }
}

// ---------- qkv GEMM: grid (64b, 4mt), 256 thr ----------
__global__ __launch_bounds__(256) void k_qkv(
    const float* __restrict__ mem, const float* __restrict__ attn_w,
    const float* __restrict__ attn_b, float* __restrict__ qkv)
{
  __shared__ float sW[192*68];
  __shared__ float sM[32*68];
  __shared__ float sBias[192];
  int b = blockIdx.x, mt = blockIdx.y, tid = threadIdx.x;
  int m0 = mt * 32;
  for (int idx = tid; idx < 12288; idx += 256) {
    int j = idx >> 6, s = idx & 63;
    sW[j*68 + s] = attn_w[idx];
  }
  for (int idx = tid; idx < 2048; idx += 256) {
    int m = idx >> 6, s = idx & 63;
    sM[m*68 + s] = mem[(size_t)b*8192 + (m0+m)*64 + s];
  }
  if (tid < 192) sBias[tid] = attn_b[tid];
  __syncthreads();
  int m = tid >> 3, js = tid & 7;
  float4 mrow[16];
#pragma unroll
  for (int r = 0; r < 16; r++) mrow[r] = *(const float4*)&sM[m*68 + r*4];
  for (int i = 0; i < 24; i++) {
    int j = js + 8*i;
    const float* wr = sW + j*68;
    float acc = sBias[j];
#pragma unroll
    for (int r = 0; r < 16; r++) acc += dot4(mrow[r], *(const float4*)&wr[r*4]);
    int ch = j >> 6, s2 = j & 63;
    qkv[((size_t)(b*3 + ch)*128 + (m0+m))*64 + s2] = acc;
  }
}

// ---------- attention + proj + LN1 + FF + LN2 (in-place mem): grid (64b, 4mt), 256 thr ----------
__global__ __launch_bounds__(256) void k_attn(
    float* __restrict__ mem, const float* __restrict__ qkv,
    const float* __restrict__ attn_ow, const float* __restrict__ attn_ob,
    const float* __restrict__ l1w, const float* __restrict__ l1b,
    const float* __restrict__ l2w, const float* __restrict__ l2b,
    const float* __restrict__ tn1g, const float* __restrict__ tn1b,
    const float* __restrict__ tn2g, const float* __restrict__ tn2b)
{
  __shared__ float P[28544];
  float* sK  = P;            // attn: [128][64] ; later sL1 [128][68]
  float* sV  = P + 8704;     // attn: [128][64] ; later sL2 [64][132]
  float* sX  = P + 17152;    // [32][68] q, then LN1 out
  float* sM  = P + 19328;    // [32][68] mem rows -> x (residual)
  float* sO  = P + 21504;    // [32][68] attn out, then ff2 out
  float* sS  = P + 23680;    // 4352: partials [256][17] -> sOW [64][68] -> sF [32][132]
  float* sRed= P + 28032;    // 512
  int b = blockIdx.x, mt = blockIdx.y, tid = threadIdx.x;
  int m0 = mt * 32;
  int lane = tid & 63, wid = tid >> 6;
  const float* qb = qkv + (size_t)b*3*8192;
  // P0 stage
  for (int i = tid*4; i < 8192; i += 1024) {
    *(float4*)&sK[i] = *(const float4*)&qb[8192 + i];
    *(float4*)&sV[i] = *(const float4*)&qb[16384 + i];
  }
  for (int i = tid*4; i < 2048; i += 1024) {
    int m = i >> 6, s = i & 63;
    *(float4*)&sX[m*68+s] = *(const float4*)&qb[m0*64 + i];
    *(float4*)&sM[m*68+s] = *(const float4*)&mem[(size_t)b*8192 + m0*64 + i];
  }
  __syncthreads();
  // P1 attention, two-pass; thread = (m, hd, half)
  int m = tid >> 3, hd = (tid >> 1) & 3, half = tid & 1;
  const float* qp = sX + m*68 + hd*16;
  float4 q0 = *(const float4*)(qp),   q1 = *(const float4*)(qp+4);
  float4 q2 = *(const float4*)(qp+8), q3 = *(const float4*)(qp+12);
  int kmb = half * 64;
  float mx = -1e30f;
#pragma unroll 4
  for (int kk = 0; kk < 64; kk++) {
    const float* kp = sK + (kmb+kk)*64 + hd*16;
    float sc = dot4(q0, *(const float4*)kp)     + dot4(q1, *(const float4*)(kp+4))
             + dot4(q2, *(const float4*)(kp+8)) + dot4(q3, *(const float4*)(kp+12));
    mx = fmaxf(mx, sc * 0.25f);
  }
  float4 o0 = {0,0,0,0}, o1 = {0,0,0,0}, o2 = {0,0,0,0}, o3 = {0,0,0,0};
  float sum = 0.f;
#pragma unroll 4
  for (int kk = 0; kk < 64; kk++) {
    const float* kp = sK + (kmb+kk)*64 + hd*16;
    float sc = dot4(q0, *(const float4*)kp)     + dot4(q1, *(const float4*)(kp+4))
             + dot4(q2, *(const float4*)(kp+8)) + dot4(q3, *(const float4*)(kp+12));
    float e = expf(sc * 0.25f - mx);
    sum += e;
    const float* vp = sV + (kmb+kk)*64 + hd*16;
    float4 v0 = *(const float4*)vp,     v1 = *(const float4*)(vp+4);
    float4 v2 = *(const float4*)(vp+8), v3 = *(const float4*)(vp+12);
    o0.x += e*v0.x; o0.y += e*v0.y; o0.z += e*v0.z; o0.w += e*v0.w;
    o1.x += e*v1.x; o1.y += e*v1.y; o1.z += e*v1.z; o1.w += e*v1.w;
    o2.x += e*v2.x; o2.y += e*v2.y; o2.z += e*v2.z; o2.w += e*v2.w;
    o3.x += e*v3.x; o3.y += e*v3.y; o3.z += e*v3.z; o3.w += e*v3.w;
  }
  {
    float* pp = sS + tid*17;
    pp[0]=o0.x; pp[1]=o0.y; pp[2]=o0.z; pp[3]=o0.w;
    pp[4]=o1.x; pp[5]=o1.y; pp[6]=o1.z; pp[7]=o1.w;
    pp[8]=o2.x; pp[9]=o2.y; pp[10]=o2.z; pp[11]=o2.w;
    pp[12]=o3.x; pp[13]=o3.y; pp[14]=o3.z; pp[15]=o3.w;
    sRed[tid] = mx; sRed[256+tid] = sum;
  }
  __syncthreads();
  if (half == 0) {
    float mx1 = sRed[tid+1], sm1 = sRed[256+tid+1];
    float M = fmaxf(mx, mx1);
    float e0 = expf(mx - M), e1 = expf(mx1 - M);
    float inv = 1.0f / (sum*e0 + sm1*e1);
    const float* pq = sS + (tid+1)*17;
    float* op = sO + m*68 + hd*16;
    op[0]  = (o0.x*e0 + pq[0]*e1)*inv;  op[1]  = (o0.y*e0 + pq[1]*e1)*inv;
    op[2]  = (o0.z*e0 + pq[2]*e1)*inv;  op[3]  = (o0.w*e0 + pq[3]*e1)*inv;
    op[4]  = (o1.x*e0 + pq[4]*e1)*inv;  op[5]  = (o1.y*e0 + pq[5]*e1)*inv;
    op[6]  = (o1.z*e0 + pq[6]*e1)*inv;  op[7]  = (o1.w*e0 + pq[7]*e1)*inv;
    op[8]  = (o2.x*e0 + pq[8]*e1)*inv;  op[9]  = (o2.y*e0 + pq[9]*e1)*inv;
    op[10] = (o2.z*e0 + pq[10]*e1)*inv; op[11] = (o2.w*e0 + pq[11]*e1)*inv;
    op[12] = (o3.x*e0 + pq[12]*e1)*inv; op[13] = (o3.y*e0 + pq[13]*e1)*inv;
    op[14] = (o3.z*e0 + pq[14]*e1)*inv; op[15] = (o3.w*e0 + pq[15]*e1)*inv;
  }
  __syncthreads();
  // stage OW (natural, pad 68) into sS
  for (int idx = tid; idx < 4096; idx += 256) {
    int j = idx >> 6, s = idx & 63;
    sS[j*68 + s] = attn_ow[idx];
  }
  __syncthreads();
  // P3 out-proj + residual -> sM (x)
  {
    int mm = tid >> 3, jset = tid & 7;
    float4 orow[16];
#pragma unroll
    for (int r = 0; r < 16; r++) orow[r] = *(const float4*)&sO[mm*68 + r*4];
#pragma unroll
    for (int i = 0; i < 8; i++) {
      int j = jset + 8*i;
      const float* wr = sS + j*68;
      float acc = attn_ob[j];
#pragma unroll
      for (int r = 0; r < 16; r++) acc += dot4(orow[r], *(const float4*)&wr[r*4]);
      sM[mm*68 + j] += acc;
    }
  }
  __syncthreads();
  // P4 LN1 -> sX ; stage sL1 (l1w natural [128][68]) and sL2 (l2w natural [64][132])
  for (int r = wid; r < 32; r += 4) {
    float v = sM[r*68 + lane];
    float ssum = wsum(v), ssq = wsum(v*v);
    float mu = ssum*(1.f/64), var = ssq*(1.f/64) - mu*mu;
    sX[r*68+lane] = (v - mu)*rsqrtf(var+1e-5f)*tn1g[lane] + tn1b[lane];
  }
  for (int idx = tid; idx < 8192; idx += 256) {
    int f = idx >> 6, s = idx & 63;
    sK[f*68 + s] = l1w[idx];
  }
  for (int idx = tid; idx < 8192; idx += 256) {
    int j = idx >> 7, s = idx & 127;
    sV[j*132 + s] = l2w[idx];
  }
  __syncthreads();
  // P5 FF1 (gelu) -> sF = sS [32][132]
  {
    int mm = tid >> 3, fs = tid & 7;
    float4 xr[16];
#pragma unroll
    for (int r = 0; r < 16; r++) xr[r] = *(const float4*)&sX[mm*68 + r*4];
#pragma unroll 4
    for (int i = 0; i < 16; i++) {
      int f = fs + 8*i;
      const float* wr = sK + f*68;
      float acc = l1b[f];
#pragma unroll
      for (int r = 0; r < 16; r++) acc += dot4(xr[r], *(const float4*)&wr[r*4]);
      sS[mm*132 + f] = 0.5f*acc*(1.0f + erff(acc*0.70710678118654752f));
    }
  }
  __syncthreads();
  // P6 FF2 + residual -> sO
  {
    int mm = tid >> 3, jset = tid & 7;
    float acc6[8];
#pragma unroll
    for (int i = 0; i < 8; i++) acc6[i] = sX[mm*68 + jset + 8*i] + l2b[jset + 8*i];
#pragma unroll
    for (int h = 0; h < 2; h++) {
      float4 fr[16];
#pragma unroll
      for (int r = 0; r < 16; r++) fr[r] = *(const float4*)&sS[mm*132 + h*64 + r*4];
#pragma unroll
      for (int i = 0; i < 8; i++) {
        int j = jset + 8*i;
        const float* wr = sV + j*132 + h*64;
        float a = 0.f;
#pragma unroll
        for (int r = 0; r < 16; r++) a += dot4(fr[r], *(const float4*)&wr[r*4]);
        acc6[i] += a;
      }
    }
#pragma unroll
    for (int i = 0; i < 8; i++) sO[mm*68 + jset + 8*i] = acc6[i];
  }
  __syncthreads();
  // P7 LN2 -> mem (in place)
  for (int r = wid; r < 32; r += 4) {
    float v = sO[r*68 + lane];
    float ssum = wsum(v), ssq = wsum(v*v);
    float mu = ssum*(1.f/64), var = ssq*(1.f/64) - mu*mu;
    mem[(size_t)b*8192 + (m0+r)*64 + lane] =
        (v - mu)*rsqrtf(var+1e-5f)*tn2g[lane] + tn2b[lane];
  }
}

// ---------- gates GEMM: grid (64 jt, 4 kt), 256 thr ----------
__global__ __launch_bounds__(256) void k_gates(
    const float* __restrict__ inbuf, const float* __restrict__ W_ih,
    const float* __restrict__ W_hh, float* __restrict__ gatesP)
{
  __shared__ float sA[32*68];
  __shared__ float sB[32*68];
  int jt = blockIdx.x, kt = blockIdx.y, tid = threadIdx.x;
  int j0 = jt*64, kbase = kt*448;
  int jq = tid >> 4, bq = tid & 15;
  int srow = tid >> 2;
  int kk = (tid & 3) * 8;
  float4 ra0, ra1, rb0, rb1;
  float acc[4][4] = {};
  {
    const float* ap = inbuf + srow*1792 + kbase + kk;
    ra0 = *(const float4*)ap; ra1 = *(const float4*)(ap+4);
    int row = j0 + srow;
    const float* bp = (kbase < 768) ? (W_ih + (size_t)row*768 + kbase + kk)
                                    : (W_hh + (size_t)row*1024 + (kbase-768) + kk);
    rb0 = *(const float4*)bp; rb1 = *(const float4*)(bp+4);
  }
  for (int c = 0; c < 14; c++) {
    __syncthreads();
#pragma unroll
    for (int i = 0; i < 4; i++) {
      sA[(kk+i)*68 + srow]   = ((const float*)&ra0)[i];
      sA[(kk+4+i)*68 + srow] = ((const float*)&ra1)[i];
      sB[(kk+i)*68 + srow]   = ((const float*)&rb0)[i];
      sB[(kk+4+i)*68 + srow] = ((const float*)&rb1)[i];
    }
    __syncthreads();
    if (c < 13) {
      int kc = kbase + (c+1)*32;
      const float* ap = inbuf + srow*1792 + kc + kk;
      ra0 = *(const float4*)ap; ra1 = *(const float4*)(ap+4);
      int row = j0 + srow;
      const float* bp = (kc < 768) ? (W_ih + (size_t)row*768 + kc + kk)
                                   : (W_hh + (size_t)row*1024 + (kc-768) + kk);
      rb0 = *(const float4*)bp; rb1 = *(const float4*)(bp+4);
    }
#pragma unroll
    for (int k = 0; k < 32; k++) {
      float4 av = *(const float4*)&sA[k*68 + bq*4];
      float4 bv = *(const float4*)&sB[k*68 + jq*4];
      acc[0][0] += bv.x*av.x; acc[0][1] += bv.x*av.y; acc[0][2] += bv.x*av.z; acc[0][3] += bv.x*av.w;
      acc[1][0] += bv.y*av.x; acc[1][1] += bv.y*av.y; acc[1][2] += bv.y*av.z; acc[1][3] += bv.y*av.w;
      acc[2][0] += bv.z*av.x; acc[2][1] += bv.z*av.y; acc[2][2] += bv.z*av.z; acc[2][3] += bv.z*av.w;
      acc[3][0] += bv.w*av.x; acc[3][1] += bv.w*av.y; acc[3][2] += bv.w*av.z; acc[3][3] += bv.w*av.w;
    }
  }
  float* gp = gatesP + (size_t)kt*262144;
#pragma unroll
  for (int bb = 0; bb < 4; bb++) {
    int b = bq*4 + bb;
    float4 r = make_float4(acc[0][bb], acc[1][bb], acc[2][bb], acc[3][bb]);
    *(float4*)&gp[b*4096 + j0 + jq*4] = r;
  }
}

// ---------- LSTM cell (+ gate partial reduce) + hn LN ----------
__global__ __launch_bounds__(256) void k_lstm(
    const float* __restrict__ gatesP, const float* __restrict__ b_ih,
    const float* __restrict__ b_hh, float* __restrict__ cbuf,
    float* __restrict__ inbuf, const float* __restrict__ cn_g,
    const float* __restrict__ cn_b, float* __restrict__ hn)
{
  __shared__ float rs[4], rq[4];
  int b = blockIdx.x, tid = threadIdx.x, lane = tid & 63, wid = tid >> 6;
  float hv[4]; float s = 0.f, sq = 0.f;
#pragma unroll
  for (int i = 0; i < 4; i++) {
    int u = tid + i * 256;
    float g4[4];
#pragma unroll
    for (int q = 0; q < 4; q++) {
      float v = b_ih[q*1024+u] + b_hh[q*1024+u];
#pragma unroll
      for (int p = 0; p < 4; p++) v += gatesP[(size_t)p*262144 + b*4096 + q*1024 + u];
      g4[q] = v;
    }
    float cn = sigm(g4[1]) * cbuf[b*1024+u] + sigm(g4[0]) * tanhf(g4[2]);
    float hh = sigm(g4[3]) * tanhf(cn);
    cbuf[b*1024+u] = cn;
    inbuf[b*1792 + 768 + u] = hh;
    hv[i] = hh; s += hh; sq += hh*hh;
  }
  s = wsum(s); sq = wsum(sq);
  if (lane == 0) { rs[wid] = s; rq[wid] = sq; }
  __syncthreads();
  float ts = rs[0]+rs[1]+rs[2]+rs[3], tq = rq[0]+rq[1]+rq[2]+rq[3];
  float mu = ts / 1024.f, var = tq / 1024.f - mu*mu;
  float rstd = rsqrtf(var + 1e-5f);
#pragma unroll
  for (int i = 0; i < 4; i++) {
    int u = tid + i * 256;
    hn[b*1024 + u] = (hv[i] - mu) * rstd * cn_g[u] + cn_b[u];
  }
}

// ---------- heads GEMM + key LN / sigmoids: grid (13 jt, 4 bt), 256 thr ----------
__global__ __launch_bounds__(256) void k_heads(
    const float* __restrict__ hn,
    const float* __restrict__ W_rk, const float* __restrict__ W_wk,
    const float* __restrict__ W_ev, const float* __restrict__ W_ws,
    const float* __restrict__ b_rk, const float* __restrict__ b_wk,
    const float* __restrict__ b_ev, const float* __restrict__ b_ws,
    const float* __restrict__ rkn_g, const float* __restrict__ rkn_b,
    const float* __restrict__ wkn_g, const float* __restrict__ wkn_b,
    float* __restrict__ rkn, float* __restrict__ wkn,
    float* __restrict__ evb, float* __restrict__ ws4)
{
  __shared__ float sA[32*17];
  __shared__ float sB[32*68];
  __shared__ float sO[64*17];
  int jt = blockIdx.x, bt = blockIdx.y, tid = threadIdx.x;
  int j0 = jt*64, bg0 = bt*16;
  const float* W; const float* bias; int base;
  if (jt < 4)       { W = W_rk; bias = b_rk; base = 0; }
  else if (jt < 8)  { W = W_wk; bias = b_wk; base = 256; }
  else if (jt < 12) { W = W_ev; bias = b_ev; base = 512; }
  else              { W = W_ws; bias = b_ws; base = 768; }
  int jq = tid >> 4, bq = tid & 15;
  int sb = tid >> 4, akk = (tid & 15) * 2;
  int sj = tid >> 2, bkk = (tid & 3) * 8;
  float a0, a1; float4 rb0, rb1;
  float acc[4] = {0,0,0,0};
  int browV = j0 + sj;
  bool bvalid = (browV < 772);
  {
    const float* ap = hn + (bg0 + sb)*1024 + akk;
    a0 = ap[0]; a1 = ap[1];
    if (bvalid) {
      const float* bp = W + (size_t)(browV-base)*1024 + bkk;
      rb0 = *(const float4*)bp; rb1 = *(const float4*)(bp+4);
    } else { rb0 = make_float4(0,0,0,0); rb1 = rb0; }
  }
  for (int c = 0; c < 32; c++) {
    __syncthreads();
    sA[(akk+0)*17 + sb] = a0;
    sA[(akk+1)*17 + sb] = a1;
#pragma unroll
    for (int i = 0; i < 4; i++) {
      sB[(bkk+i)*68 + sj]   = ((const float*)&rb0)[i];
      sB[(bkk+4+i)*68 + sj] = ((const float*)&rb1)[i];
    }
    __syncthreads();
    if (c < 31) {
      int kc = (c+1)*32;
      const float* ap = hn + (bg0 + sb)*1024 + kc + akk;
      a0 = ap[0]; a1 = ap[1];
      if (bvalid) {
        const float* bp = W + (size_t)(browV-base)*1024 + kc + bkk;
        rb0 = *(const float4*)bp; rb1 = *(const float4*)(bp+4);
      }
    }
#pragma unroll
    for (int k = 0; k < 32; k++) {
      float av = sA[k*17 + bq];
      float4 bv = *(const float4*)&sB[k*68 + jq*4];
      acc[0] += bv.x*av; acc[1] += bv.y*av; acc[2] += bv.z*av; acc[3] += bv.w*av;
    }
  }
  int b = bg0 + bq;
  if (jt >= 8 && jt < 12) {
#pragma unroll
    for (int jj = 0; jj < 4; jj++) {
      int row = j0 + jq*4 + jj;
      evb[b*256 + (row-512)] = sigm(acc[jj] + bias[row-base]);
    }
  } else if (jt == 12) {
    if (jq == 0) {
#pragma unroll
      for (int jj = 0; jj < 4; jj++) ws4[b*4 + jj] = sigm(acc[jj] + bias[jj]);
    }
  } else {
#pragma unroll
    for (int jj = 0; jj < 4; jj++) {
      int row = j0 + jq*4 + jj;
      sO[(jq*4+jj)*17 + bq] = acc[jj] + bias[row-base];
    }
    __syncthreads();
    int lane = tid & 63, wid = tid >> 6;
    int head = jt & 3;
    float* dst = (jt < 4) ? rkn : wkn;
    const float* gg = (jt < 4) ? rkn_g : wkn_g;
    const float* bb2 = (jt < 4) ? rkn_b : wkn_b;
#pragma unroll
    for (int i = 0; i < 4; i++) {
      int bl = wid*4 + i;
      float v = sO[lane*17 + bl];
      float ssum = wsum(v), ssq = wsum(v*v);
      float mu = ssum*(1.f/64), var = ssq*(1.f/64) - mu*mu;
      float r = (v - mu)*rsqrtf(var+1e-5f)*gg[lane] + bb2[lane];
      dst[(bg0+bl)*256 + head*64 + lane] = r;
    }
  }
}

// ---------- NTM addressing + mem update + output LN + next xin: grid 64, 256 thr ----------
__global__ __launch_bounds__(256) void k_address(
    float* __restrict__ mem,
    const float* __restrict__ rkn, const float* __restrict__ wkn,
    const float* __restrict__ evb, const float* __restrict__ ws4,
    const float* __restrict__ hn,
    const float* __restrict__ mng, const float* __restrict__ mnb,
    const float* __restrict__ pog, const float* __restrict__ pob,
    const float* __restrict__ x_emb, const float* __restrict__ in_g,
    const float* __restrict__ in_b,
    float* __restrict__ inbuf, float* __restrict__ pobuf, int tnext)
{
  __shared__ float sMT[8192];
  __shared__ float sMN[128*65];
  __shared__ float sRk[256], sWk[256], sEv[256], sWs[4];
  __shared__ float sRw[512], sWw[512], sRc[256];
  __shared__ float rs[4], rq[4];
  int b = blockIdx.x, tid = threadIdx.x, lane = tid & 63, wid = tid >> 6;
  for (int i = tid*4; i < 8192; i += 1024)
    *(float4*)&sMT[i] = *(const float4*)&mem[(size_t)b*8192 + i];
  sRk[tid] = rkn[b*256 + tid]; sWk[tid] = wkn[b*256 + tid]; sEv[tid] = evb[b*256 + tid];
  if (tid < 4) sWs[tid] = ws4[b*4 + tid];
  __syncthreads();
  // mem_n
  for (int r = wid; r < 128; r += 4) {
    float v = sMT[r*64 + lane];
    float ssum = wsum(v), ssq = wsum(v*v);
    float mu = ssum*(1.f/64), var = ssq*(1.f/64) - mu*mu;
    sMN[r*65 + lane] = (v - mu)*rsqrtf(var+1e-5f)*mng[lane] + mnb[lane];
  }
  __syncthreads();
  // scores
#pragma unroll
  for (int q = 0; q < 4; q++) {
    int idx = tid + q*256;
    int which = idx >> 9;
    int n = (idx >> 7) & 3, m = idx & 127;
    const float* key = (which ? sWk : sRk) + n*64;
    const float* mr = sMN + m*65;
    float acc = 0.f;
#pragma unroll 8
    for (int k = 0; k < 64; k++) acc += key[k]*mr[k];
    (which ? sWw : sRw)[n*128 + m] = acc;
  }
  __syncthreads();
  // softmax (8 rows of 128)
  for (int r = wid; r < 8; r += 4) {
    float* row = (r < 4) ? (sRw + r*128) : (sWw + (r-4)*128);
    float a0 = row[lane], a1 = row[lane+64];
    float mx = fmaxf(a0, a1);
#pragma unroll
    for (int o = 32; o > 0; o >>= 1) mx = fmaxf(mx, __shfl_xor(mx, o, 64));
    float e0 = expf(a0 - mx), e1 = expf(a1 - mx);
    float inv = 1.0f / wsum(e0 + e1);
    row[lane] = e0*inv; row[lane+64] = e1*inv;
  }
  __syncthreads();
  // rc = rw @ mem(tblock out)
  {
    int n = tid >> 6, s2 = tid & 63;
    float acc = 0.f;
    for (int mm = 0; mm < 128; mm++) acc += sRw[n*128 + mm] * sMT[mm*64 + s2];
    sRc[tid] = acc;
  }
  __syncthreads();
  // mem update (in place)
  for (int idx = tid; idx < 8192; idx += 256) {
    int mm = idx >> 6, s2 = idx & 63;
    float er = 0.f, ad = 0.f;
#pragma unroll
    for (int n = 0; n < 4; n++) {
      float w = sWw[n*128 + mm];
      er += w * sEv[n*64 + s2];
      ad += w * sWs[n] * sWk[n*64 + s2];
    }
    mem[(size_t)b*8192 + idx] = sMT[idx]*(1.0f - er) + ad;
  }
  // output LN over 1280 = [hn | rc]
  float v5[5]; float s = 0.f, sq = 0.f;
#pragma unroll
  for (int i = 0; i < 5; i++) {
    int k = tid + i*256;
    float v = (k < 1024) ? hn[b*1024 + k] : sRc[k-1024];
    v5[i] = v; s += v; sq += v*v;
  }
  s = wsum(s); sq = wsum(sq);
  if (lane == 0) { rs[wid] = s; rq[wid] = sq; }
  __syncthreads();
  {
    float ts = rs[0]+rs[1]+rs[2]+rs[3], tq = rq[0]+rq[1]+rq[2]+rq[3];
    float mu = ts/1280.f, var = tq/1280.f - mu*mu;
    float rstd = rsqrtf(var + 1e-5f);
#pragma unroll
    for (int i = 0; i < 5; i++) {
      int k = tid + i*256;
      pobuf[b*1280 + k] = (v5[i] - mu)*rstd*pog[k] + pob[k];
    }
  }
  // next-step xin = ln(concat(x_{t+1}, rc))
  if (tnext < 256) {
    __syncthreads();
    float v3[3]; float s2 = 0.f, q2 = 0.f;
#pragma unroll
    for (int i = 0; i < 3; i++) {
      int k = tid + i*256;
      float v = (k < 512) ? x_emb[((size_t)b*256 + tnext)*512 + k] : sRc[k-512];
      v3[i] = v; s2 += v; q2 += v*v;
    }
    s2 = wsum(s2); q2 = wsum(q2);
    if (lane == 0) { rs[wid] = s2; rq[wid] = q2; }
    __syncthreads();
    float ts = rs[0]+rs[1]+rs[2]+rs[3], tq = rq[0]+rq[1]+rq[2]+rq[3];
    float mu = ts/768.f, var = tq/768.f - mu*mu;
    float rstd = rsqrtf(var + 1e-5f);
#pragma unroll
    for (int i = 0; i < 3; i++) {
      int k = tid + i*256;
      inbuf[b*1792 + k] = (v3[i] - mu)*rstd*in_g[k] + in_b[k];
    }
  }
}

// ---------- logits GEMM: grid (16 jt, 4 bt), 256 thr ----------
__global__ __launch_bounds__(256) void k_logits(
    const float* __restrict__ pobuf, const float* __restrict__ W_proj,
    const float* __restrict__ b_proj, float* __restrict__ outs, int t)
{
  __shared__ float sA[32*17];
  __shared__ float sB[32*68];
  int jt = blockIdx.x, bt = blockIdx.y, tid = threadIdx.x;
  int j0 = jt*64, b0 = bt*16;
  int jq = tid >> 4, bq = tid & 15;
  int sbb = tid >> 4, akk = (tid & 15) * 2;
  int sj = tid >> 2, bkk = (tid & 3) * 8;
  float a0, a1; float4 rb0, rb1;
  float acc[4] = {0,0,0,0};
  {
    const float* ap = pobuf + (b0+sbb)*1280 + akk;
    a0 = ap[0]; a1 = ap[1];
    const float* bp = W_proj + (size_t)(j0+sj)*1280 + bkk;
    rb0 = *(const float4*)bp; rb1 = *(const float4*)(bp+4);
  }
  for (int c = 0; c < 40; c++) {
    __syncthreads();
    sA[(akk+0)*17 + sbb] = a0;
    sA[(akk+1)*17 + sbb] = a1;
#pragma unroll
    for (int i = 0; i < 4; i++) {
      sB[(bkk+i)*68 + sj]   = ((const float*)&rb0)[i];
      sB[(bkk+4+i)*68 + sj] = ((const float*)&rb1)[i];
    }
    __syncthreads();
    if (c < 39) {
      int kc = (c+1)*32;
      const float* ap = pobuf + (b0+sbb)*1280 + kc + akk;
      a0 = ap[0]; a1 = ap[1];
      const float* bp = W_proj + (size_t)(j0+sj)*1280 + kc + bkk;
      rb0 = *(const float4*)bp; rb1 = *(const float4*)(bp+4);
    }
#pragma unroll
    for (int k = 0; k < 32; k++) {
      float av = sA[k*17 + bq];
      float4 bv = *(const float4*)&sB[k*68 + jq*4];
      acc[0] += bv.x*av; acc[1] += bv.y*av; acc[2] += bv.z*av; acc[3] += bv.w*av;
    }
  }
  int b = b0 + bq;
  int j = j0 + jq*4;
  float4 r;
  r.x = acc[0] + b_proj[j+0]; r.y = acc[1] + b_proj[j+1];
  r.z = acc[2] + b_proj[j+2]; r.w = acc[3] + b_proj[j+3];
  *(float4*)&outs[((size_t)b*256 + t)*1024 + j] = r;
}

// ---------- final copy ----------
__global__ void k_final(const float* __restrict__ mem, const float* __restrict__ inbuf,
                        const float* __restrict__ cbuf, float* __restrict__ out)
{
  int i = blockIdx.x * 256 + threadIdx.x;
  if (i < 524288) out[16777216 + i] = mem[i];
  if (i < 65536) {
    int b = i >> 10, u = i & 1023;
    out[17301504 + i] = inbuf[b*1792 + 768 + u];
    out[17367040 + i] = cbuf[i];
  }
}

extern "C" void kernel_launch(void* const* d_in, const int* in_sizes, int n_in,
                              void* d_out, int out_size, void* d_ws, size_t ws_size,
                              hipStream_t stream) {
  const float* x_emb  = (const float*)d_in[0];
  const float* in_g   = (const float*)d_in[1];
  const float* in_b   = (const float*)d_in[2];
  const float* W_ih   = (const float*)d_in[3];
  const float* W_hh   = (const float*)d_in[4];
  const float* b_ih   = (const float*)d_in[5];
  const float* b_hh   = (const float*)d_in[6];
  const float* cn_g   = (const float*)d_in[7];
  const float* cn_b   = (const float*)d_in[8];
  const float* W_rk   = (const float*)d_in[9];
  const float* b_rk   = (const float*)d_in[10];
  const float* W_wk   = (const float*)d_in[11];
  const float* b_wk   = (const float*)d_in[12];
  const float* W_ws   = (const float*)d_in[13];
  const float* b_ws   = (const float*)d_in[14];
  const float* W_ev   = (const float*)d_in[15];
  const float* b_ev   = (const float*)d_in[16];
  const float* attn_w = (const float*)d_in[17];
  const float* attn_b = (const float*)d_in[18];
  const float* attn_ow= (const float*)d_in[19];
  const float* attn_ob= (const float*)d_in[20];
  const float* l1_w   = (const float*)d_in[21];
  const float* l1_b   = (const float*)d_in[22];
  const float* l2_w   = (const float*)d_in[23];
  const float* l2_b   = (const float*)d_in[24];
  const float* tn1_g  = (const float*)d_in[25];
  const float* tn1_b  = (const float*)d_in[26];
  const float* tn2_g  = (const float*)d_in[27];
  const float* tn2_b  = (const float*)d_in[28];
  const float* rkn_g  = (const float*)d_in[29];
  const float* rkn_b  = (const float*)d_in[30];
  const float* wkn_g  = (const float*)d_in[31];
  const float* wkn_b  = (const float*)d_in[32];
  const float* mn_g   = (const float*)d_in[33];
  const float* mn_b   = (const float*)d_in[34];
  const float* po_g   = (const float*)d_in[35];
  const float* po_b   = (const float*)d_in[36];
  const float* W_proj = (const float*)d_in[37];
  const float* b_proj = (const float*)d_in[38];

  float* ws = (float*)d_ws;
  float* mem    = ws;                 // 524288
  float* cbuf   = ws + 524288;        // 65536
  float* inbuf  = ws + 589824;        // 114688
  float* gatesP = ws + 704512;        // 1048576 (4 x 64 x 4096)
  float* hn     = ws + 1753088;       // 65536
  float* rkn    = ws + 1818624;       // 16384
  float* wkn    = ws + 1835008;       // 16384
  float* evb    = ws + 1851392;       // 16384
  float* ws4    = ws + 1867776;       // 256
  float* pobuf  = ws + 1868032;       // 81920
  float* qkvb   = ws + 1949952;       // 1572864 (end 3522816)

  hipMemsetAsync(d_ws, 0, 704512 * sizeof(float), stream);  // mem, cbuf, inbuf
  k_prep0<<<64, 256, 0, stream>>>(x_emb, in_g, in_b, inbuf);

  for (int t = 0; t < 256; t++) {
    k_qkv<<<dim3(64,4), 256, 0, stream>>>(mem, attn_w, attn_b, qkvb);
    k_gates<<<dim3(64,4), 256, 0, stream>>>(inbuf, W_ih, W_hh, gatesP);
    k_attn<<<dim3(64,4), 256, 0, stream>>>(mem, qkvb, attn_ow, attn_ob,
                                           l1_w, l1_b, l2_w, l2_b,
                                           tn1_g, tn1_b, tn2_g, tn2_b);
    k_lstm<<<64, 256, 0, stream>>>(gatesP, b_ih, b_hh, cbuf, inbuf, cn_g, cn_b, hn);
    k_heads<<<dim3(13,4), 256, 0, stream>>>(hn, W_rk, W_wk, W_ev, W_ws,
                                            b_rk, b_wk, b_ev, b_ws,
                                            rkn_g, rkn_b, wkn_g, wkn_b,
                                            rkn, wkn, evb, ws4);
    k_address<<<64, 256, 0, stream>>>(mem, rkn, wkn, evb, ws4, hn,
                                      mn_g, mn_b, po_g, po_b,
                                      x_emb, in_g, in_b, inbuf, pobuf, t+1);
    k_logits<<<dim3(16,4), 256, 0, stream>>>(pobuf, W_proj, b_proj, (float*)d_out, t);
  }
  k_final<<<2048, 256, 0, stream>>>(mem, inbuf, cbuf, (float*)d_out);
}